// Round 17
// baseline (47.633 us; speedup 1.0000x reference)
//
#include <hip/hip_runtime.h>
#include <math.h>

#define HEADS 4
#define DH 64
#define CH 256
#define HW 4096
#define HH 64
#define WW 64
#define BB 2

#define NPOS 224        // union: 14 uy x 16 ux (ux 14,15 always masked, P=0)
#define ROWB 448        // bytes per KVT LDS row (224 bf16)

typedef __attribute__((ext_vector_type(8))) short bf16x8;
typedef __attribute__((ext_vector_type(4))) float f32x4;
typedef __attribute__((ext_vector_type(4))) short short4_t;
typedef __attribute__((ext_vector_type(4))) unsigned u32x4;

// Paired f32->bf16 RNE convert (1 instruction; no builtin on gfx950).
__device__ __forceinline__ unsigned cvt_pk_bf16(float lo, float hi) {
  unsigned r;
  asm("v_cvt_pk_bf16_f32 %0, %1, %2" : "=v"(r) : "v"(lo), "v"(hi));
  return r;
}

// XOR swizzle on byte address (write and read sides use the same formula).
__device__ __forceinline__ int swz(int row, int byte_off) {
  return byte_off ^ ((row & 7) << 4);
}

// ---------------- MFMA projection: out[b][pix][o] = sum_c in[b][c][pix] * W[o][c]
// grid (HW/64, BB, 12) [proven shape]. Block 256 = 4 waves; wave owns
// 16 pixels x 64 outs. Round-17: W-stage split into two 32-row halves ->
// LDS 32 KB -> 16 KB, lifting occupancy from 5 blocks/CU (1280 slots, 20%
// second dispatch round for the 1536-block grid) to ~6 blocks/CU (all 1536
// resident in one round) and giving ~6 waves/SIMD to hide A-gather latency.
// Swizzle is (ol&7); o = h2*32+ol and 32 = 0 mod 8, so read==write mapping.
__global__ __launch_bounds__(256) void proj_mfma_kernel(
    const float* __restrict__ qmap, const float* __restrict__ kvmap1,
    const float* __restrict__ kvmap2, const float* __restrict__ Wq,
    const float* __restrict__ Wkv, short* __restrict__ Qt,
    short* __restrict__ KV1, short* __restrict__ KV2) {
  const float* in; const float* Wf; short* out; float wsc;
  switch (blockIdx.z >> 2) {
    case 0:  in = qmap;   Wf = Wq;  out = Qt;  wsc = 0.125f; break;
    case 1:  in = kvmap1; Wf = Wkv; out = KV1; wsc = 1.0f;   break;
    default: in = kvmap2; Wf = Wkv; out = KV2; wsc = 1.0f;   break;
  }
  __shared__ short wl[32 * 256];                        // 16 KB, swizzled [ol][c]
  const int ng = blockIdx.z & 3;                        // out-channel group (64)
  const int b = blockIdx.y, t = threadIdx.x;
  const int w = t >> 6, lane = t & 63, l15 = lane & 15, lg = lane >> 4;

  // A-gather first (issue early; latency hides under W-stage + barrier)
  const int pix = blockIdx.x * 64 + w * 16 + l15;       // A-row for this lane
  const float* inb = in + (size_t)b * CH * HW;
  u32x4 aw[8];                                          // c = k8*32 + lg*8 + j
  #pragma unroll
  for (int k8 = 0; k8 < 8; ++k8) {
    float f[8];
    #pragma unroll
    for (int j = 0; j < 8; ++j)
      f[j] = inb[(size_t)(k8 * 32 + lg * 8 + j) * HW + pix];
    #pragma unroll
    for (int jw = 0; jw < 4; ++jw)
      aw[k8][jw] = cvt_pk_bf16(f[2 * jw], f[2 * jw + 1]);
  }

  const int prow = blockIdx.x * 64 + w * 16 + lg * 4;   // C-row base for store
  short* ob = out + (size_t)b * HW * CH;
  const float* wsrc = Wf + (size_t)(ng * 64) * CH;

  #pragma unroll
  for (int h2 = 0; h2 < 2; ++h2) {
    if (h2) __syncthreads();           // protect wl from previous readers
    // stage 32 W rows (f32 -> bf16 inline): 2048 float4, 8 per thread
    #pragma unroll
    for (int i = 0; i < 8; ++i) {
      int idx = i * 256 + t;
      int ol = idx >> 6, q4 = idx & 63;                 // ol in [0,32)
      float4 v = *(const float4*)(wsrc + (h2 * 32 + ol) * CH + q4 * 4);
      uint2 pkw;
      pkw.x = cvt_pk_bf16(v.x * wsc, v.y * wsc);
      pkw.y = cvt_pk_bf16(v.z * wsc, v.w * wsc);
      int s = q4 >> 1, hh = q4 & 1;
      *(uint2*)((char*)wl + ol * 512 + ((s * 16) ^ ((ol & 7) * 16)) + hh * 8) = pkw;
    }
    __syncthreads();

    #pragma unroll
    for (int nq2 = 0; nq2 < 2; ++nq2) {
      const int nt = ng * 4 + h2 * 2 + nq2;
      const int ol = nq2 * 16 + l15;                    // local W row
      f32x4 acc = (f32x4)0.f;
      #pragma unroll
      for (int k8 = 0; k8 < 8; ++k8) {
        bf16x8 bfrag = *(const bf16x8*)((char*)wl + ol * 512 +
                                        (((k8 * 4 + lg) * 16) ^ ((ol & 7) * 16)));
        acc = __builtin_amdgcn_mfma_f32_16x16x32_bf16(
            __builtin_bit_cast(bf16x8, aw[k8]), bfrag, acc, 0, 0, 0);
      }
      #pragma unroll
      for (int r = 0; r < 4; ++r)
        ob[(size_t)(prow + r) * CH + nt * 16 + l15] =
            (short)(cvt_pk_bf16(acc[r], acc[r]) & 0xffffu);
    }
  }
}

// ---------------- MFMA local attention (exact r15 form, best verified)
// block = (b*4+n, 8x8 pixel tile); 4 waves; wave w owns pixel rows 2w,2w+1
// and union rows uy in [2w, 2w+7]. KVT columns stored in permuted order
// pos' = 32*(uy>>1) + 8*(ux>>2) + 4*(uy&1) + (ux&3), so PV's A-fragment is
// the lane's OWN softmax registers (no WT buffer, no shuffles).
// Barrier sits after softmax (S'/softmax never touch KVT). Max-free softmax
// (logits ~N(0,1); expf overflows at 88). P packed via v_cvt_pk_bf16_f32.
// s_setprio(1) around the PV MFMA cluster (T5).
__global__ __launch_bounds__(256, 4) void attn_kernel(
    const short* __restrict__ Qt, const short* __restrict__ KV1,
    const short* __restrict__ KV2, float* __restrict__ out) {
  __shared__ char KVT[64 * ROWB];    // [d][pos' 224] bf16, swizzled (28 KB)

  const int t = threadIdx.x, lane = t & 63, w = t >> 6;
  const int l15 = lane & 15, lg = lane >> 4;
  const int bn = blockIdx.x, b = bn >> 2, n = bn & 3;
  const int tile = blockIdx.y;
  const int ty = tile >> 3, tx = tile & 7;

  bf16x8 qf0, qf1;
  {
    int p = w * 16 + l15;
    int gp = (ty * 8 + (p >> 3)) * 64 + tx * 8 + (p & 7);
    const short* qb = Qt + ((size_t)b * HW + gp) * CH + n * DH + lg * 8;
    qf0 = *(const bf16x8*)(qb);
    qf1 = *(const bf16x8*)(qb + 32);
  }

  f32x4 acc2[4];
  #pragma unroll
  for (int i = 0; i < 4; ++i) acc2[i] = (f32x4)0.f;

  const int p = w * 16 + l15, px = p & 7;
  const int hi8 = l15 >> 3;            // pixel row within wave's pair

  #pragma unroll
  for (int br = 0; br < 2; ++br) {
    const short* kv = (br ? KV2 : KV1) + (size_t)b * HW * CH + n * DH;
    if (br) __syncthreads();           // all waves' PV reads of KVT complete

    // ---- build KVT[d][pos']: 448 (4pos x 8d) tiles over 2 rounds ----
    #pragma unroll
    for (int it = 0; it < 2; ++it) {
      int tid = it * 256 + t;
      if (tid < 448) {
        int dc = (tid * 586) >> 15;          // tid / 56 (exact for tid < 448)
        int posT = tid - dc * 56;
        int pos0 = posT * 4;
        int uy = pos0 >> 4, ux0 = pos0 & 15; // ux0 in {0,4,8,12}
        int colp = 32 * (uy >> 1) + 8 * (ux0 >> 2) + 4 * (uy & 1); // pos' base
        int gy = ty * 8 + uy - 3;
        bool yok = (gy >= 0) && (gy < HH);
        bf16x8 v[4];
        #pragma unroll
        for (int r = 0; r < 4; ++r) {
          int ux = ux0 + r;
          int gx = tx * 8 + ux - 3;
          bool valid = yok && (ux < 14) && (gx >= 0) && (gx < WW);
          v[r] = (bf16x8)0;
          if (valid)
            v[r] = *(const bf16x8*)(kv + (size_t)(gy * WW + gx) * CH + dc * 8);
        }
        #pragma unroll
        for (int j = 0; j < 8; ++j) {
          int d = dc * 8 + j;
          short4_t pk;
          pk[0] = v[0][j]; pk[1] = v[1][j]; pk[2] = v[2][j]; pk[3] = v[3][j];
          *(short4_t*)(KVT + swz(d, d * ROWB + colp * 2)) = pk;
        }
      }
    }
    // NO barrier here: S'/softmax are KVT-independent.

    // ---- S' tiles, wave-local rows uy = 2w+i, i=0..7 (A from global) ----
    f32x4 sa[8];
    {
      int ux = l15;
      int gx = tx * 8 + ux - 3;
      bool xok = (ux < 14) && (gx >= 0) && (gx < WW);
      #pragma unroll
      for (int i = 0; i < 8; ++i) {
        int gy = ty * 8 + (2 * w + i) - 3;
        bool valid = xok && (gy >= 0) && (gy < HH);
        bf16x8 a0 = (bf16x8)0, a1 = (bf16x8)0;
        if (valid) {
          const short* src = kv + (size_t)(gy * WW + gx) * CH + lg * 8;
          a0 = *(const bf16x8*)(src);
          a1 = *(const bf16x8*)(src + 32);
        }
        f32x4 s = (f32x4)0.f;
        s = __builtin_amdgcn_mfma_f32_16x16x32_bf16(a0, qf0, s, 0, 0, 0);
        s = __builtin_amdgcn_mfma_f32_16x16x32_bf16(a1, qf1, s, 0, 0, 0);
        sa[i] = s;
      }
    }

    // ---- softmax over pos, max-free (logits ~N(0,1), overflow at 88) ----
    float den = 0.f;
    #pragma unroll
    for (int i = 0; i < 8; ++i) {
      int dy = i - hi8;
      bool yok = (dy >= 0) && (dy <= 6);
      #pragma unroll
      for (int r = 0; r < 4; ++r) {
        int dx = (lg * 4 + r) - px;
        bool in = yok && (dx >= 0) && (dx <= 6);
        float e = in ? __expf(sa[i][r]) : 0.f;   // window-OOB -> weight 0
        sa[i][r] = e;
        den += e;
      }
    }
    den += __shfl_xor(den, 16, 64);
    den += __shfl_xor(den, 32, 64);
    float inv = 1.f / den;

    // ---- normalize + pack P to bf16 words (cvt_pk), all in-register ----
    unsigned pw0[8], pw1[8];
    #pragma unroll
    for (int i = 0; i < 8; ++i) {
      pw0[i] = cvt_pk_bf16(sa[i][0] * inv, sa[i][1] * inv);
      pw1[i] = cvt_pk_bf16(sa[i][2] * inv, sa[i][3] * inv);
    }

    __syncthreads();                    // KVT writes visible to all waves

    // ---- PV: O[pix][d] += P x V; A = own packed words, B = KVT b128 ----
    __builtin_amdgcn_s_setprio(1);
    #pragma unroll
    for (int kp = 0; kp < 4; ++kp) {
      int gposb = (32 * w + kp * 32 + lg * 8) * 2;   // KVT pos' byte
      u32x4 aw = {pw0[2 * kp], pw1[2 * kp], pw0[2 * kp + 1], pw1[2 * kp + 1]};
      bf16x8 af = __builtin_bit_cast(bf16x8, aw);
      #pragma unroll
      for (int ntp = 0; ntp < 4; ++ntp) {
        int brow = ntp * 16 + l15;
        bf16x8 bf = *(const bf16x8*)(KVT + swz(brow, brow * ROWB + gposb));
        acc2[ntp] = __builtin_amdgcn_mfma_f32_16x16x32_bf16(af, bf, acc2[ntp], 0, 0, 0);
      }
    }
    __builtin_amdgcn_s_setprio(0);
  }

  // ---- epilogue: average branches, store f32x4 (4 consecutive pixels) ----
  int p0 = w * 16 + lg * 4;
  int gp = (ty * 8 + (p0 >> 3)) * 64 + tx * 8 + (p0 & 7);
  #pragma unroll
  for (int ntp = 0; ntp < 4; ++ntp) {
    int o = n * DH + ntp * 16 + l15;
    f32x4 v = acc2[ntp] * 0.5f;
    *(f32x4*)(out + ((size_t)b * CH + o) * HW + gp) = v;
  }
}

extern "C" void kernel_launch(void* const* d_in, const int* in_sizes, int n_in,
                              void* d_out, int out_size, void* d_ws, size_t ws_size,
                              hipStream_t stream) {
  const float* kvmap1 = (const float*)d_in[0];
  const float* qmap   = (const float*)d_in[1];
  const float* kvmap2 = (const float*)d_in[2];
  const float* Wq     = (const float*)d_in[3];
  const float* Wkv    = (const float*)d_in[4];
  float* out = (float*)d_out;

  // workspace: bf16 Qt | KV1 | KV2 (4 MB each = 12 MB)
  short* Qt  = (short*)d_ws;
  short* KV1 = Qt  + (size_t)BB * HW * CH;
  short* KV2 = KV1 + (size_t)BB * HW * CH;

  dim3 pgrid(HW / 64, BB, 12);
  proj_mfma_kernel<<<pgrid, 256, 0, stream>>>(qmap, kvmap1, kvmap2, Wq, Wkv,
                                              Qt, KV1, KV2);

  dim3 agrid(BB * HEADS, 64);
  attn_kernel<<<agrid, 256, 0, stream>>>(Qt, KV1, KV2, out);
}

// Round 18
// 33.903 us; speedup vs baseline: 1.4050x; 1.4050x over previous
//
#include <hip/hip_runtime.h>
#include <math.h>

#define HEADS 4
#define DH 64
#define CH 256
#define HW 4096
#define HH 64
#define WW 64
#define BB 2

#define NPOS 224        // union: 14 uy x 16 ux (ux 14,15 always masked, P=0)
#define ROWB 448        // bytes per KVT LDS row (224 bf16)

typedef __attribute__((ext_vector_type(8))) short bf16x8;
typedef __attribute__((ext_vector_type(4))) float f32x4;
typedef __attribute__((ext_vector_type(4))) short short4_t;
typedef __attribute__((ext_vector_type(4))) unsigned u32x4;

// Paired f32->bf16 RNE convert (1 instruction; no builtin on gfx950).
__device__ __forceinline__ unsigned cvt_pk_bf16(float lo, float hi) {
  unsigned r;
  asm("v_cvt_pk_bf16_f32 %0, %1, %2" : "=v"(r) : "v"(lo), "v"(hi));
  return r;
}

// XOR swizzle on byte address (write and read sides use the same formula).
__device__ __forceinline__ int swz(int row, int byte_off) {
  return byte_off ^ ((row & 7) << 4);
}

// ---------------- MFMA projection: out[b][pix][o] = sum_c in[b][c][pix] * W[o][c]
// grid (HW/64, BB, 12): z = input*4 + out-channel-group. Block 256 = 4 waves;
// wave owns 16 pixels x 64 outs. W staged f32->bf16 inline into LDS (q-scale
// 0.125 folded before rounding: exact pow2). Single-barrier schedule: W-stage
// and A-gather overlap, one __syncthreads, then 4 N-tiles of MFMA.
// (r17's two-half W-split with 4 barriers/block regressed 13.7 us — the
// stage/compute overlap, not LDS occupancy, is what matters here.)
__global__ __launch_bounds__(256) void proj_mfma_kernel(
    const float* __restrict__ qmap, const float* __restrict__ kvmap1,
    const float* __restrict__ kvmap2, const float* __restrict__ Wq,
    const float* __restrict__ Wkv, short* __restrict__ Qt,
    short* __restrict__ KV1, short* __restrict__ KV2) {
  const float* in; const float* Wf; short* out; float wsc;
  switch (blockIdx.z >> 2) {
    case 0:  in = qmap;   Wf = Wq;  out = Qt;  wsc = 0.125f; break;
    case 1:  in = kvmap1; Wf = Wkv; out = KV1; wsc = 1.0f;   break;
    default: in = kvmap2; Wf = Wkv; out = KV2; wsc = 1.0f;   break;
  }
  __shared__ short wl[64 * 256];                        // 32 KB, swizzled [o'][c]
  const int ng = blockIdx.z & 3;                        // out-channel group (64)
  const int b = blockIdx.y, t = threadIdx.x;
  const int w = t >> 6, lane = t & 63, l15 = lane & 15, lg = lane >> 4;

  // cooperative W stage: 64 rows x 256 f32 = 4096 float4; float4 -> 2 cvt_pk
  {
    const float* wsrc = Wf + (size_t)(ng * 64) * CH;
    #pragma unroll
    for (int i = 0; i < 16; ++i) {
      int idx = i * 256 + t;
      int o = idx >> 6, q4 = idx & 63;
      float4 v = *(const float4*)(wsrc + o * CH + q4 * 4);   // coalesced
      uint2 pkw;
      pkw.x = cvt_pk_bf16(v.x * wsc, v.y * wsc);
      pkw.y = cvt_pk_bf16(v.z * wsc, v.w * wsc);
      int s = q4 >> 1, h = q4 & 1;
      *(uint2*)((char*)wl + o * 512 + ((s * 16) ^ ((o & 7) * 16)) + h * 8) = pkw;
    }
  }

  // A-gather (direct strided dwords), overlaps the W stage
  const int pix = blockIdx.x * 64 + w * 16 + l15;       // A-row for this lane
  const float* inb = in + (size_t)b * CH * HW;
  u32x4 aw[8];                                          // c = k8*32 + lg*8 + j
  #pragma unroll
  for (int k8 = 0; k8 < 8; ++k8) {
    float f[8];
    #pragma unroll
    for (int j = 0; j < 8; ++j)
      f[j] = inb[(size_t)(k8 * 32 + lg * 8 + j) * HW + pix];
    #pragma unroll
    for (int jw = 0; jw < 4; ++jw)
      aw[k8][jw] = cvt_pk_bf16(f[2 * jw], f[2 * jw + 1]);
  }
  __syncthreads();

  const int prow = blockIdx.x * 64 + w * 16 + lg * 4;   // C-row base for store
  short* ob = out + (size_t)b * HW * CH;
  #pragma unroll
  for (int nq = 0; nq < 4; ++nq) {
    const int nt = ng * 4 + nq;
    const int o = nq * 16 + l15;                        // local W row
    f32x4 acc = (f32x4)0.f;
    #pragma unroll
    for (int k8 = 0; k8 < 8; ++k8) {
      bf16x8 bfrag = *(const bf16x8*)((char*)wl + o * 512 +
                                      (((k8 * 4 + lg) * 16) ^ ((o & 7) * 16)));
      acc = __builtin_amdgcn_mfma_f32_16x16x32_bf16(
          __builtin_bit_cast(bf16x8, aw[k8]), bfrag, acc, 0, 0, 0);
    }
    #pragma unroll
    for (int r = 0; r < 4; ++r)
      ob[(size_t)(prow + r) * CH + nt * 16 + l15] =
          (short)(cvt_pk_bf16(acc[r], acc[r]) & 0xffffu);
  }
}

// ---------------- MFMA local attention
// block = (b*4+n, 8x8 pixel tile); 4 waves; wave w owns pixel rows 2w,2w+1
// and union rows uy in [2w, 2w+7]. KVT columns stored in permuted order
// pos' = 32*(uy>>1) + 8*(ux>>2) + 4*(uy&1) + (ux&3), so PV's A-fragment is
// the lane's OWN softmax registers (no WT buffer, no shuffles).
// Barrier sits after softmax (S'/softmax never touch KVT). Max-free softmax
// (logits ~N(0,1); expf overflows at 88). P packed via v_cvt_pk_bf16_f32.
// s_setprio(1) around the PV MFMA cluster (T5).
__global__ __launch_bounds__(256, 4) void attn_kernel(
    const short* __restrict__ Qt, const short* __restrict__ KV1,
    const short* __restrict__ KV2, float* __restrict__ out) {
  __shared__ char KVT[64 * ROWB];    // [d][pos' 224] bf16, swizzled (28 KB)

  const int t = threadIdx.x, lane = t & 63, w = t >> 6;
  const int l15 = lane & 15, lg = lane >> 4;
  const int bn = blockIdx.x, b = bn >> 2, n = bn & 3;
  const int tile = blockIdx.y;
  const int ty = tile >> 3, tx = tile & 7;

  bf16x8 qf0, qf1;
  {
    int p = w * 16 + l15;
    int gp = (ty * 8 + (p >> 3)) * 64 + tx * 8 + (p & 7);
    const short* qb = Qt + ((size_t)b * HW + gp) * CH + n * DH + lg * 8;
    qf0 = *(const bf16x8*)(qb);
    qf1 = *(const bf16x8*)(qb + 32);
  }

  f32x4 acc2[4];
  #pragma unroll
  for (int i = 0; i < 4; ++i) acc2[i] = (f32x4)0.f;

  const int p = w * 16 + l15, px = p & 7;
  const int hi8 = l15 >> 3;            // pixel row within wave's pair

  #pragma unroll
  for (int br = 0; br < 2; ++br) {
    const short* kv = (br ? KV2 : KV1) + (size_t)b * HW * CH + n * DH;
    if (br) __syncthreads();           // all waves' PV reads of KVT complete

    // ---- build KVT[d][pos']: 448 (4pos x 8d) tiles over 2 rounds ----
    #pragma unroll
    for (int it = 0; it < 2; ++it) {
      int tid = it * 256 + t;
      if (tid < 448) {
        int dc = (tid * 586) >> 15;          // tid / 56 (exact for tid < 448)
        int posT = tid - dc * 56;
        int pos0 = posT * 4;
        int uy = pos0 >> 4, ux0 = pos0 & 15; // ux0 in {0,4,8,12}
        int colp = 32 * (uy >> 1) + 8 * (ux0 >> 2) + 4 * (uy & 1); // pos' base
        int gy = ty * 8 + uy - 3;
        bool yok = (gy >= 0) && (gy < HH);
        bf16x8 v[4];
        #pragma unroll
        for (int r = 0; r < 4; ++r) {
          int ux = ux0 + r;
          int gx = tx * 8 + ux - 3;
          bool valid = yok && (ux < 14) && (gx >= 0) && (gx < WW);
          v[r] = (bf16x8)0;
          if (valid)
            v[r] = *(const bf16x8*)(kv + (size_t)(gy * WW + gx) * CH + dc * 8);
        }
        #pragma unroll
        for (int j = 0; j < 8; ++j) {
          int d = dc * 8 + j;
          short4_t pk;
          pk[0] = v[0][j]; pk[1] = v[1][j]; pk[2] = v[2][j]; pk[3] = v[3][j];
          *(short4_t*)(KVT + swz(d, d * ROWB + colp * 2)) = pk;
        }
      }
    }
    // NO barrier here: S'/softmax are KVT-independent.

    // ---- S' tiles, wave-local rows uy = 2w+i, i=0..7 (A from global) ----
    f32x4 sa[8];
    {
      int ux = l15;
      int gx = tx * 8 + ux - 3;
      bool xok = (ux < 14) && (gx >= 0) && (gx < WW);
      #pragma unroll
      for (int i = 0; i < 8; ++i) {
        int gy = ty * 8 + (2 * w + i) - 3;
        bool valid = xok && (gy >= 0) && (gy < HH);
        bf16x8 a0 = (bf16x8)0, a1 = (bf16x8)0;
        if (valid) {
          const short* src = kv + (size_t)(gy * WW + gx) * CH + lg * 8;
          a0 = *(const bf16x8*)(src);
          a1 = *(const bf16x8*)(src + 32);
        }
        f32x4 s = (f32x4)0.f;
        s = __builtin_amdgcn_mfma_f32_16x16x32_bf16(a0, qf0, s, 0, 0, 0);
        s = __builtin_amdgcn_mfma_f32_16x16x32_bf16(a1, qf1, s, 0, 0, 0);
        sa[i] = s;
      }
    }

    // ---- softmax over pos, max-free (logits ~N(0,1), overflow at 88) ----
    float den = 0.f;
    #pragma unroll
    for (int i = 0; i < 8; ++i) {
      int dy = i - hi8;
      bool yok = (dy >= 0) && (dy <= 6);
      #pragma unroll
      for (int r = 0; r < 4; ++r) {
        int dx = (lg * 4 + r) - px;
        bool in = yok && (dx >= 0) && (dx <= 6);
        float e = in ? __expf(sa[i][r]) : 0.f;   // window-OOB -> weight 0
        sa[i][r] = e;
        den += e;
      }
    }
    den += __shfl_xor(den, 16, 64);
    den += __shfl_xor(den, 32, 64);
    float inv = 1.f / den;

    // ---- normalize + pack P to bf16 words (cvt_pk), all in-register ----
    unsigned pw0[8], pw1[8];
    #pragma unroll
    for (int i = 0; i < 8; ++i) {
      pw0[i] = cvt_pk_bf16(sa[i][0] * inv, sa[i][1] * inv);
      pw1[i] = cvt_pk_bf16(sa[i][2] * inv, sa[i][3] * inv);
    }

    __syncthreads();                    // KVT writes visible to all waves

    // ---- PV: O[pix][d] += P x V; A = own packed words, B = KVT b128 ----
    __builtin_amdgcn_s_setprio(1);
    #pragma unroll
    for (int kp = 0; kp < 4; ++kp) {
      int gposb = (32 * w + kp * 32 + lg * 8) * 2;   // KVT pos' byte
      u32x4 aw = {pw0[2 * kp], pw1[2 * kp], pw0[2 * kp + 1], pw1[2 * kp + 1]};
      bf16x8 af = __builtin_bit_cast(bf16x8, aw);
      #pragma unroll
      for (int ntp = 0; ntp < 4; ++ntp) {
        int brow = ntp * 16 + l15;
        bf16x8 bf = *(const bf16x8*)(KVT + swz(brow, brow * ROWB + gposb));
        acc2[ntp] = __builtin_amdgcn_mfma_f32_16x16x32_bf16(af, bf, acc2[ntp], 0, 0, 0);
      }
    }
    __builtin_amdgcn_s_setprio(0);
  }

  // ---- epilogue: average branches, store f32x4 (4 consecutive pixels) ----
  int p0 = w * 16 + lg * 4;
  int gp = (ty * 8 + (p0 >> 3)) * 64 + tx * 8 + (p0 & 7);
  #pragma unroll
  for (int ntp = 0; ntp < 4; ++ntp) {
    int o = n * DH + ntp * 16 + l15;
    f32x4 v = acc2[ntp] * 0.5f;
    *(f32x4*)(out + ((size_t)b * CH + o) * HW + gp) = v;
  }
}

extern "C" void kernel_launch(void* const* d_in, const int* in_sizes, int n_in,
                              void* d_out, int out_size, void* d_ws, size_t ws_size,
                              hipStream_t stream) {
  const float* kvmap1 = (const float*)d_in[0];
  const float* qmap   = (const float*)d_in[1];
  const float* kvmap2 = (const float*)d_in[2];
  const float* Wq     = (const float*)d_in[3];
  const float* Wkv    = (const float*)d_in[4];
  float* out = (float*)d_out;

  // workspace: bf16 Qt | KV1 | KV2 (4 MB each = 12 MB)
  short* Qt  = (short*)d_ws;
  short* KV1 = Qt  + (size_t)BB * HW * CH;
  short* KV2 = KV1 + (size_t)BB * HW * CH;

  dim3 pgrid(HW / 64, BB, 12);
  proj_mfma_kernel<<<pgrid, 256, 0, stream>>>(qmap, kvmap1, kvmap2, Wq, Wkv,
                                              Qt, KV1, KV2);

  dim3 agrid(BB * HEADS, 64);
  attn_kernel<<<agrid, 256, 0, stream>>>(Qt, KV1, KV2, out);
}